// Round 2
// baseline (17596.956 us; speedup 1.0000x reference)
//
#include <hip/hip_runtime.h>
#include <math.h>

// GRU B=64,T=512,I=512,H=1024 fp32. Split-bf16 (hi+lo) MFMA path:
//   acc += Ahi*Bhi + Ahi*Blo + Alo*Bhi   (~2^-17 relative error, ~fp32)
// Weights + x pre-split once per launch into d_ws (needs ~86.5MB);
// h split in step epilogue into ping-pong planes. Step kernel: 64 blocks
// (16 j's each, 3 gates), 256 thr = 4 waves (wave = 16 batch rows), no LDS,
// no barriers. B-frags stored in ws in exact MFMA B-fragment order ->
// coalesced 1KB loads. Fallback to fp32 VALU kernel if ws too small.

typedef __attribute__((ext_vector_type(8))) short short8;
typedef __attribute__((ext_vector_type(4))) float f32x4;
typedef unsigned short u16;
typedef unsigned int u32;

#define TT 512
#define BB 64
#define II 512
#define HH 1024
#define JT 16
#define NBLK 64
#define NKS 48        // k-steps of 32 over K=1536 (16 x-part + 32 h-part)
#define NKS_X 16

// ---- ws layout (bytes) ----
#define SZ_WPL (3ULL*64*48*512*2)          // 9,437,184 per weight plane
#define OFF_WHI 0ULL
#define OFF_WLO (OFF_WHI + SZ_WPL)
#define SZ_XPL (512ULL*64*512*2)           // 33,554,432 per x plane
#define OFF_XHI (OFF_WLO + SZ_WPL)
#define OFF_XLO (OFF_XHI + SZ_XPL)
#define SZ_HPL (2ULL*64*1024*2)            // 262,144 (2 parities)
#define OFF_HHI (OFF_XLO + SZ_XPL)
#define OFF_HLO (OFF_HHI + SZ_HPL)
#define WS_NEEDED (OFF_HLO + SZ_HPL)       // 86,507,520

__device__ __forceinline__ u16 f2bf(float f) {
    u32 u = __float_as_uint(f);
    u32 r = (u + 0x7FFFu + ((u >> 16) & 1u)) >> 16;   // RNE
    return (u16)r;
}
__device__ __forceinline__ float bf2f(u16 h) {
    return __uint_as_float(((u32)h) << 16);
}

// ---------------- prep kernels (once per launch) ----------------

// Weight planes in B-fragment order: el index ((g*64+jt)*48+ks)*512 + lane*8 + e
// holds W_g[j = jt*16 + (lane&15)][k = ks*32 + (lane>>4)*8 + e] (k<512 -> W_i, else W_h).
__global__ __launch_bounds__(256) void prep_w(
    const float* __restrict__ Wir, const float* __restrict__ Whr,
    const float* __restrict__ Wiz, const float* __restrict__ Whz,
    const float* __restrict__ Win, const float* __restrict__ Whn,
    u16* __restrict__ whi, u16* __restrict__ wlo)
{
    int id = blockIdx.x * 256 + threadIdx.x;       // < 589824
    int lane = id & 63;
    int qq = id >> 6;                               // (g*64+jt)*48+ks
    int ks = qq % 48;
    int rr = qq / 48;
    int g = rr >> 6;
    int jt = rr & 63;
    int j = jt * 16 + (lane & 15);
    int k = ks * 32 + (lane >> 4) * 8;
    const float* Wi = (g == 0) ? Wir : (g == 1) ? Wiz : Win;
    const float* Wh = (g == 0) ? Whr : (g == 1) ? Whz : Whn;
    const float* src = (k < II) ? (Wi + (size_t)j * II + k)
                                : (Wh + (size_t)j * HH + (k - II));
    short8 H, L;
#pragma unroll
    for (int e = 0; e < 8; ++e) {
        float f = src[e];
        u16 hi = f2bf(f);
        u16 lo = f2bf(f - bf2f(hi));
        H[e] = (short)hi;
        L[e] = (short)lo;
    }
    size_t dst = (size_t)qq * 512 + (size_t)lane * 8;
    *(short8*)(whi + dst) = H;
    *(short8*)(wlo + dst) = L;
}

// x planes: xhi[(t*64 + b)*512 + i]  (transpose b<->t from x[b][t][i])
__global__ __launch_bounds__(256) void prep_x(
    const float* __restrict__ x, u16* __restrict__ xhi, u16* __restrict__ xlo)
{
    int id = blockIdx.x * 256 + threadIdx.x;       // < 2,097,152
    int t = id >> 12;
    int b = (id >> 6) & 63;
    int i8 = id & 63;
    const float* src = x + ((size_t)b * TT + t) * II + i8 * 8;
    short8 H, L;
#pragma unroll
    for (int e = 0; e < 8; ++e) {
        float f = src[e];
        u16 hi = f2bf(f);
        u16 lo = f2bf(f - bf2f(hi));
        H[e] = (short)hi;
        L[e] = (short)lo;
    }
    size_t dst = ((size_t)t * 64 + b) * II + (size_t)i8 * 8;
    *(short8*)(xhi + dst) = H;
    *(short8*)(xlo + dst) = L;
}

// ---------------- MFMA step kernel ----------------

#define LD8(p) (*(const short8*)(p))
#define MFMA16(a, b, c) __builtin_amdgcn_mfma_f32_16x16x32_bf16((a), (b), (c), 0, 0, 0)

__global__ __launch_bounds__(256) void gru_step_mfma(
    const u16* __restrict__ xhi, const u16* __restrict__ xlo,
    const u16* __restrict__ whi, const u16* __restrict__ wlo,
    const u16* __restrict__ hhi_r, const u16* __restrict__ hlo_r,
    u16* __restrict__ hhi_w, u16* __restrict__ hlo_w,
    const float* __restrict__ bir, const float* __restrict__ bhr,
    const float* __restrict__ biz, const float* __restrict__ bhz,
    const float* __restrict__ bin_, const float* __restrict__ bhn,
    float* __restrict__ out, int t)
{
    const int tid = threadIdx.x;
    const int w = tid >> 6;          // wave id: M-tile (rows 16w..16w+15)
    const int lane = tid & 63;
    const int q = lane >> 4;
    const int nn = lane & 15;
    const int jt = blockIdx.x;       // 0..63
    const int j = jt * JT + nn;

    f32x4 accR = {0.f, 0.f, 0.f, 0.f};
    f32x4 accZ = {0.f, 0.f, 0.f, 0.f};
    f32x4 accNx = {0.f, 0.f, 0.f, 0.f};
    f32x4 accNh = {0.f, 0.f, 0.f, 0.f};

    const int rowA = w * 16 + nn;    // A-frag row (batch)
    const size_t GS = (size_t)64 * 48 * 512;     // els per gate in W planes
    const u16* axh = xhi + ((size_t)t * 64 + rowA) * II + q * 8;
    const u16* axl = xlo + ((size_t)t * 64 + rowA) * II + q * 8;
    const size_t wb = (size_t)jt * 48 * 512 + (size_t)lane * 8;
    const u16* bwh = whi + wb;
    const u16* bwl = wlo + wb;

    // ---- x part: Ks = 0..15 ----
#pragma unroll 4
    for (int Ks = 0; Ks < NKS_X; ++Ks) {
        short8 ah = LD8(axh + Ks * 32);
        short8 al = LD8(axl + Ks * 32);
        const u16* b0 = bwh + (size_t)Ks * 512;
        const u16* l0 = bwl + (size_t)Ks * 512;
        short8 bh, bl;
        bh = LD8(b0);            bl = LD8(l0);
        accR = MFMA16(ah, bh, accR); accR = MFMA16(ah, bl, accR); accR = MFMA16(al, bh, accR);
        bh = LD8(b0 + GS);       bl = LD8(l0 + GS);
        accZ = MFMA16(ah, bh, accZ); accZ = MFMA16(ah, bl, accZ); accZ = MFMA16(al, bh, accZ);
        bh = LD8(b0 + 2 * GS);   bl = LD8(l0 + 2 * GS);
        accNx = MFMA16(ah, bh, accNx); accNx = MFMA16(ah, bl, accNx); accNx = MFMA16(al, bh, accNx);
    }

    // ---- h part: Ks = 16..47 (skip at t==0, h=0) ----
    if (t > 0) {
        const u16* ahh = hhi_r + (size_t)rowA * HH + q * 8;
        const u16* ahl = hlo_r + (size_t)rowA * HH + q * 8;
#pragma unroll 4
        for (int K2 = 0; K2 < 32; ++K2) {
            short8 ah = LD8(ahh + K2 * 32);
            short8 al = LD8(ahl + K2 * 32);
            const u16* b0 = bwh + (size_t)(NKS_X + K2) * 512;
            const u16* l0 = bwl + (size_t)(NKS_X + K2) * 512;
            short8 bh, bl;
            bh = LD8(b0);            bl = LD8(l0);
            accR = MFMA16(ah, bh, accR); accR = MFMA16(ah, bl, accR); accR = MFMA16(al, bh, accR);
            bh = LD8(b0 + GS);       bl = LD8(l0 + GS);
            accZ = MFMA16(ah, bh, accZ); accZ = MFMA16(ah, bl, accZ); accZ = MFMA16(al, bh, accZ);
            bh = LD8(b0 + 2 * GS);   bl = LD8(l0 + 2 * GS);
            accNh = MFMA16(ah, bh, accNh); accNh = MFMA16(ah, bl, accNh); accNh = MFMA16(al, bh, accNh);
        }
    }

    // ---- epilogue: C/D layout col=lane&15, row=(lane>>4)*4+reg ----
    const float vbir = bir[j], vbhr = bhr[j];
    const float vbiz = biz[j], vbhz = bhz[j];
    const float vbin = bin_[j], vbhn = bhn[j];
#pragma unroll
    for (int e = 0; e < 4; ++e) {
        int row = w * 16 + q * 4 + e;
        float rp = accR[e] + vbir + vbhr;
        float zp = accZ[e] + vbiz + vbhz;
        float hn = accNh[e] + vbhn;
        float xn = accNx[e] + vbin;
        float rg = 1.f / (1.f + __expf(-rp));
        float zg = 1.f / (1.f + __expf(-zp));
        float ng = tanhf(xn + rg * hn);
        float hp = (t > 0) ? out[((size_t)row * TT + (t - 1)) * HH + j] : 0.f;
        float hv = (1.f - zg) * ng + zg * hp;
        out[((size_t)row * TT + t) * HH + j] = hv;
        u16 hh = f2bf(hv);
        u16 hl = f2bf(hv - bf2f(hh));
        hhi_w[(size_t)row * HH + j] = hh;
        hlo_w[(size_t)row * HH + j] = hl;
    }
}

// ---------------- fallback fp32 kernel (round-1, known-passing) ----------------

#define CK 128
#define PAD 132

__device__ __forceinline__ void fma4(float4& a, const float4 xv, const float4 w) {
    a.x += xv.x * w.x; a.y += xv.y * w.y; a.z += xv.z * w.z; a.w += xv.w * w.w;
}

__device__ __forceinline__ void accum_chunk(
    const float* __restrict__ xsrow,
    const float* __restrict__ wr, const float* __restrict__ wz,
    const float* __restrict__ wn, float4& aR, float4& aZ, float4& aN)
{
#pragma unroll
    for (int k4 = 0; k4 < CK / 4; ++k4) {
        float4 xv = *(const float4*)(xsrow + k4 * 4);
        fma4(aR, xv, *(const float4*)(wr + k4 * 4));
        fma4(aZ, xv, *(const float4*)(wz + k4 * 4));
        fma4(aN, xv, *(const float4*)(wn + k4 * 4));
    }
}

__global__ __launch_bounds__(256) void gru_step_f32(
    const float* __restrict__ x,
    const float* __restrict__ Wir, const float* __restrict__ Whr,
    const float* __restrict__ Wiz, const float* __restrict__ Whz,
    const float* __restrict__ Win, const float* __restrict__ Whn,
    const float* __restrict__ bir, const float* __restrict__ bhr,
    const float* __restrict__ biz, const float* __restrict__ bhz,
    const float* __restrict__ bin_, const float* __restrict__ bhn,
    float* __restrict__ out, int t)
{
    __shared__ float xs[BB][PAD];
    const int tid = threadIdx.x;
    const int b = tid & 63;
    const int jg = tid >> 6;
    const int j = __builtin_amdgcn_readfirstlane((int)blockIdx.x * 4 + jg);

    float4 aR = {0,0,0,0}, aZ = {0,0,0,0}, aXN = {0,0,0,0}, aHN = {0,0,0,0};

    const float* xbase = x + (size_t)t * II;
    for (int kc = 0; kc < II / CK; ++kc) {
#pragma unroll
        for (int i = 0; i < 8; ++i) {
            int f = tid + 256 * i; int row = f >> 5; int c4 = f & 31;
            *(float4*)&xs[row][c4 * 4] =
                *(const float4*)(xbase + (size_t)row * (TT * II) + kc * CK + c4 * 4);
        }
        __syncthreads();
        accum_chunk(&xs[b][0], Wir + (size_t)j * II + kc * CK,
                    Wiz + (size_t)j * II + kc * CK, Win + (size_t)j * II + kc * CK,
                    aR, aZ, aXN);
        __syncthreads();
    }
    if (t > 0) {
        const float* hbase = out + (size_t)(t - 1) * HH;
        for (int kc = 0; kc < HH / CK; ++kc) {
#pragma unroll
            for (int i = 0; i < 8; ++i) {
                int f = tid + 256 * i; int row = f >> 5; int c4 = f & 31;
                *(float4*)&xs[row][c4 * 4] =
                    *(const float4*)(hbase + (size_t)row * (TT * HH) + kc * CK + c4 * 4);
            }
            __syncthreads();
            accum_chunk(&xs[b][0], Whr + (size_t)j * HH + kc * CK,
                        Whz + (size_t)j * HH + kc * CK, Whn + (size_t)j * HH + kc * CK,
                        aR, aZ, aHN);
            __syncthreads();
        }
    }
    float rpre = (aR.x + aR.y + aR.z + aR.w) + bir[j] + bhr[j];
    float zpre = (aZ.x + aZ.y + aZ.z + aZ.w) + biz[j] + bhz[j];
    float hn = (aHN.x + aHN.y + aHN.z + aHN.w) + bhn[j];
    float xn = (aXN.x + aXN.y + aXN.z + aXN.w) + bin_[j];
    float r = 1.f / (1.f + __expf(-rpre));
    float z = 1.f / (1.f + __expf(-zpre));
    float n = tanhf(xn + r * hn);
    float hprev = (t > 0) ? out[(size_t)b * (TT * HH) + (size_t)(t - 1) * HH + j] : 0.f;
    float hnew = (1.f - z) * n + z * hprev;
    out[(size_t)b * (TT * HH) + (size_t)t * HH + j] = hnew;
}

// ---------------- host ----------------

extern "C" void kernel_launch(void* const* d_in, const int* in_sizes, int n_in,
                              void* d_out, int out_size, void* d_ws, size_t ws_size,
                              hipStream_t stream) {
    (void)in_sizes; (void)n_in; (void)out_size;

    const float* x    = (const float*)d_in[0];
    const float* Wir  = (const float*)d_in[1];
    const float* bir  = (const float*)d_in[2];
    const float* Whr  = (const float*)d_in[3];
    const float* bhr  = (const float*)d_in[4];
    const float* Wiz  = (const float*)d_in[5];
    const float* biz  = (const float*)d_in[6];
    const float* Whz  = (const float*)d_in[7];
    const float* bhz  = (const float*)d_in[8];
    const float* Win  = (const float*)d_in[9];
    const float* bin_ = (const float*)d_in[10];
    const float* Whn  = (const float*)d_in[11];
    const float* bhn  = (const float*)d_in[12];
    float* out = (float*)d_out;

    if (ws_size < WS_NEEDED) {
        // fallback: fp32 VALU path
        for (int t = 0; t < TT; ++t) {
            gru_step_f32<<<dim3(HH / 4), dim3(256), 0, stream>>>(
                x, Wir, Whr, Wiz, Whz, Win, Whn,
                bir, bhr, biz, bhz, bin_, bhn, out, t);
        }
        return;
    }

    unsigned char* ws = (unsigned char*)d_ws;
    u16* whi = (u16*)(ws + OFF_WHI);
    u16* wlo = (u16*)(ws + OFF_WLO);
    u16* xhi = (u16*)(ws + OFF_XHI);
    u16* xlo = (u16*)(ws + OFF_XLO);
    u16* hhi = (u16*)(ws + OFF_HHI);
    u16* hlo = (u16*)(ws + OFF_HLO);

    prep_w<<<dim3(589824 / 256), dim3(256), 0, stream>>>(
        Wir, Whr, Wiz, Whz, Win, Whn, whi, wlo);
    prep_x<<<dim3(2097152 / 256), dim3(256), 0, stream>>>(x, xhi, xlo);

    for (int t = 0; t < TT; ++t) {
        int wp = t & 1;            // write parity
        int rp = wp ^ 1;           // read parity (= (t-1)&1 for t>=1)
        gru_step_mfma<<<dim3(NBLK), dim3(256), 0, stream>>>(
            xhi, xlo, whi, wlo,
            hhi + (size_t)rp * (BB * HH), hlo + (size_t)rp * (BB * HH),
            hhi + (size_t)wp * (BB * HH), hlo + (size_t)wp * (BB * HH),
            bir, bhr, biz, bhz, bin_, bhn, out, t);
    }
}